// Round 6
// baseline (271.156 us; speedup 1.0000x reference)
//
#include <hip/hip_runtime.h>
#include <hip/hip_bf16.h>
#include <math.h>

#define B_ 16
#define D_ 64
#define T_ 4096
#define K_ 1024
#define BT_ (B_*T_)

// output layout (flat f32, concatenated in return order)
#define ZQ_OFF   0
#define LOSS_OFF 4194304
#define IDX_OFF  4194305
#define PERP_OFF 4259841
#define HIST_OFF 4259842

typedef __attribute__((ext_vector_type(8))) short bf16x8;
typedef __attribute__((ext_vector_type(4))) float f32x4;

__device__ __forceinline__ unsigned umin_(unsigned a, unsigned b){ return a < b ? a : b; }
__device__ __forceinline__ unsigned umax_(unsigned a, unsigned b){ return a > b ? a : b; }

__device__ __forceinline__ ushort f2bf(float x) {
  __hip_bfloat16 h = __float2bfloat16(x);
  return *(ushort*)&h;
}
__device__ __forceinline__ float bf2f(ushort u) {
  __hip_bfloat16 h; *(ushort*)&h = u;
  return __bfloat162float(h);
}

// ---- prep: zero counters + emb f32 -> (ebh, ebl) bf16 split + e_sq ----
// 4096 threads: 1024 codes x 4 chunks of 16 dims
__global__ __launch_bounds__(256) void prep_kernel(
    const float* __restrict__ emb, int* __restrict__ zero_ws,
    float* __restrict__ e_sq, ushort* __restrict__ ebh, ushort* __restrict__ ebl) {
  const int tid = blockIdx.x * 256 + threadIdx.x;
  if (tid < 1026) zero_ws[tid] = 0;   // counts[1024] + commit + done
  const int k = tid >> 2, q = tid & 3;
  const float4* p = (const float4*)(emb + (size_t)k * D_ + q * 16);
  bf16x8 vh[2], vl[2];
  float s = 0.f;
#pragma unroll
  for (int i = 0; i < 4; ++i) {
    float4 v = p[i];
    float xs[4] = {v.x, v.y, v.z, v.w};
#pragma unroll
    for (int j = 0; j < 4; ++j) {
      float x = xs[j];
      ushort hb = f2bf(x);
      ushort lb = f2bf(x - bf2f(hb));
      vh[i >> 1][(i & 1) * 4 + j] = (short)hb;
      vl[i >> 1][(i & 1) * 4 + j] = (short)lb;
      s = fmaf(x, x, s);
    }
  }
  size_t off = (size_t)k * D_ + q * 16;
  *(bf16x8*)(ebh + off) = vh[0];
  *(bf16x8*)(ebh + off + 8) = vh[1];
  *(bf16x8*)(ebl + off) = vl[0];
  *(bf16x8*)(ebl + off + 8) = vl[1];
  s += __shfl_xor(s, 1, 64);
  s += __shfl_xor(s, 2, 64);
  if (q == 0) e_sq[k] = s;
}

__device__ double dist64row(const float* __restrict__ zb, int r,
                            const float* __restrict__ emb, int k) {
  double s = 0.0, dot = 0.0;
#pragma unroll
  for (int d = 0; d < D_; ++d) {
    double e = (double)emb[(size_t)k * D_ + d];
    double x = (double)zb[(size_t)d * T_ + r];
    s += e * e;
    dot += x * e;
  }
  return s - 2.0 * dot;
}

// ---- main: 64 rows/block, 4 waves x 256-code quadrant, MFMA bf16-split ----
__global__ __launch_bounds__(256, 3) void vq_mfma(
    const float* __restrict__ z_e, const float* __restrict__ emb_f32,
    const float* __restrict__ e_sq, const ushort* __restrict__ ebh,
    const ushort* __restrict__ ebl, float* __restrict__ out,
    float* __restrict__ commit_ws, int* __restrict__ counts,
    int* __restrict__ done) {
  __shared__ ushort Ah[64 * 64];
  __shared__ ushort Al[64 * 64];
  __shared__ unsigned mrg1[4][64];
  __shared__ unsigned mrg2[4][64];
  __shared__ int idx_sh[64];
  __shared__ float cred[256];
  __shared__ int ticket_sh;

  const int tid = threadIdx.x;
  const int lane = tid & 63, wave = tid >> 6;
  const int b = blockIdx.x >> 6;
  const int t0 = (blockIdx.x & 63) << 6;
  const float* zbase = z_e + ((size_t)b * D_) * T_ + t0;

  // Phase 0: stage A tile (64 rows x 64 d) as bf16 hi/lo, XOR-swizzled rows
  {
    const int r = tid & 63, d0 = (tid >> 6) * 16;
    bf16x8 vh[2], vl[2];
#pragma unroll
    for (int j = 0; j < 16; ++j) {
      float x = zbase[(size_t)(d0 + j) * T_ + r];
      ushort hb = f2bf(x);
      vh[j >> 3][j & 7] = (short)hb;
      vl[j >> 3][j & 7] = (short)f2bf(x - bf2f(hb));
    }
    const int base = r * 128 + d0 * 2;
    const int swz = (r & 7) << 4;
    *(bf16x8*)((char*)Ah + (base ^ swz)) = vh[0];
    *(bf16x8*)((char*)Ah + ((base + 16) ^ swz)) = vh[1];
    *(bf16x8*)((char*)Al + (base ^ swz)) = vl[0];
    *(bf16x8*)((char*)Al + ((base + 16) ^ swz)) = vl[1];
  }
  __syncthreads();

  // A fragments to registers (reused for all 16 slabs): [rowfrag][kstep]
  bf16x8 afh[4][2], afl[4][2];
  {
    const int ar = lane & 15;
    const int aks = (lane >> 4) * 8;
#pragma unroll
    for (int f = 0; f < 4; ++f)
#pragma unroll
      for (int ks = 0; ks < 2; ++ks) {
        const int row = f * 16 + ar;
        const int col = ks * 32 + aks;
        const int off = (row * 128 + col * 2) ^ ((row & 7) << 4);
        afh[f][ks] = *(bf16x8*)((char*)Ah + off);
        afl[f][ks] = *(bf16x8*)((char*)Al + off);
      }
  }

  const int cw0 = wave * 256;  // wave's code base (wave-uniform)
  const size_t boff = (size_t)(cw0 + (lane & 15)) * D_ + (lane >> 4) * 8;

  unsigned b1[4][4], b2[4][4];
#pragma unroll
  for (int f = 0; f < 4; ++f)
#pragma unroll
    for (int r = 0; r < 4; ++r) { b1[f][r] = 0xFFFFFFFFu; b2[f][r] = 0xFFFFFFFFu; }

  bf16x8 cbh[2][2], cbl[2][2];
  float cesq[2];
#define LOADB(s, buf)                                                   \
  { size_t o = boff + (size_t)(s) * 16 * D_;                            \
    cbh[buf][0] = *(const bf16x8*)(ebh + o);                            \
    cbh[buf][1] = *(const bf16x8*)(ebh + o + 32);                       \
    cbl[buf][0] = *(const bf16x8*)(ebl + o);                            \
    cbl[buf][1] = *(const bf16x8*)(ebl + o + 32);                       \
    cesq[buf] = e_sq[cw0 + (s) * 16 + (lane & 15)]; }

  LOADB(0, 0);
#pragma unroll
  for (int s = 0; s < 16; ++s) {
    const int cur = s & 1, nxt = cur ^ 1;
    if (s < 15) LOADB(s + 1, nxt);
    f32x4 acc[4];
#pragma unroll
    for (int f = 0; f < 4; ++f) acc[f] = (f32x4){0.f, 0.f, 0.f, 0.f};
#pragma unroll
    for (int f = 0; f < 4; ++f) {
      acc[f] = __builtin_amdgcn_mfma_f32_16x16x32_bf16(afh[f][0], cbh[cur][0], acc[f], 0, 0, 0);
      acc[f] = __builtin_amdgcn_mfma_f32_16x16x32_bf16(afh[f][1], cbh[cur][1], acc[f], 0, 0, 0);
      acc[f] = __builtin_amdgcn_mfma_f32_16x16x32_bf16(afl[f][0], cbh[cur][0], acc[f], 0, 0, 0);
      acc[f] = __builtin_amdgcn_mfma_f32_16x16x32_bf16(afl[f][1], cbh[cur][1], acc[f], 0, 0, 0);
      acc[f] = __builtin_amdgcn_mfma_f32_16x16x32_bf16(afh[f][0], cbl[cur][0], acc[f], 0, 0, 0);
      acc[f] = __builtin_amdgcn_mfma_f32_16x16x32_bf16(afh[f][1], cbl[cur][1], acc[f], 0, 0, 0);
    }
    const unsigned code = (unsigned)(cw0 + s * 16 + (lane & 15));
#pragma unroll
    for (int f = 0; f < 4; ++f) {
#pragma unroll
      for (int r = 0; r < 4; ++r) {
        float dist = fmaf(acc[f][r], -2.0f, cesq[cur]);
        unsigned u = __float_as_uint(dist);
        unsigned sk = u ^ (unsigned)(((int)u >> 31) | 0x80000000);
        unsigned key = (sk & 0xFFFFFC00u) | code;
        unsigned t = umax_(b1[f][r], key);
        b1[f][r] = umin_(b1[f][r], key);
        b2[f][r] = umin_(b2[f][r], t);
      }
    }
  }
#undef LOADB

  // cross-lane top-2 merge across the 16 col-slots (lane bits 0..3)
#pragma unroll
  for (int m = 1; m < 16; m <<= 1) {
#pragma unroll
    for (int f = 0; f < 4; ++f)
#pragma unroll
      for (int r = 0; r < 4; ++r) {
        unsigned o1 = (unsigned)__shfl_xor((int)b1[f][r], m, 64);
        unsigned o2 = (unsigned)__shfl_xor((int)b2[f][r], m, 64);
        unsigned t = umax_(b1[f][r], o1);
        b1[f][r] = umin_(b1[f][r], o1);
        b2[f][r] = umin_(umin_(b2[f][r], o2), t);
      }
  }
  if ((lane & 15) == 0) {
    const int g = lane >> 4;
#pragma unroll
    for (int f = 0; f < 4; ++f)
#pragma unroll
      for (int r = 0; r < 4; ++r) {
        const int row = f * 16 + g * 4 + r;
        mrg1[wave][row] = b1[f][r];
        mrg2[wave][row] = b2[f][r];
      }
  }
  __syncthreads();

  // Phase 2: merge 4 wave-quadrants per row, f64 recheck near-ties, emit index
  if (tid < 64) {
    const int r = tid;
    unsigned B1 = 0xFFFFFFFFu, B2 = 0xFFFFFFFFu;
#pragma unroll
    for (int w = 0; w < 4; ++w) {
      unsigned o1 = mrg1[w][r], o2 = mrg2[w][r];
      unsigned t = umax_(B1, o1);
      B1 = umin_(B1, o1);
      B2 = umin_(umin_(B2, o2), t);
    }
    int i1 = (int)(B1 & 1023u);
    const int i2 = (int)(B2 & 1023u);
    if ((B2 & ~1023u) - (B1 & ~1023u) <= (8u << 10)) {
      double d1 = dist64row(zbase, r, emb_f32, i1);
      double d2 = dist64row(zbase, r, emb_f32, i2);
      if (d2 < d1 || (d2 == d1 && i2 < i1)) i1 = i2;
    }
    idx_sh[r] = i1;
    out[IDX_OFF + b * T_ + t0 + r] = (float)i1;
    atomicAdd(&counts[i1], 1);
  }
  __syncthreads();

  // Phase 3: gather z_q (exact f32), write out, exact commit-loss partial
  {
    const int r = tid & 63, d0 = (tid >> 6) * 16;
    const int k = idx_sh[r];
    const float* ep = emb_f32 + (size_t)k * D_ + d0;
    float c = 0.f;
#pragma unroll
    for (int j = 0; j < 16; ++j) {
      float e = ep[j];
      float x = zbase[(size_t)(d0 + j) * T_ + r];
      out[ZQ_OFF + ((size_t)b * D_ + d0 + j) * T_ + t0 + r] = e;
      float df = x - e;
      c = fmaf(df, df, c);
    }
#pragma unroll
    for (int off = 32; off; off >>= 1) c += __shfl_down(c, off, 64);
    if (lane == 0) cred[wave] = c;
  }
  __syncthreads();
  if (tid == 0) atomicAdd(commit_ws, cred[0] + cred[1] + cred[2] + cred[3]);

  // Folded finalize: last block to finish computes hist/perplexity/loss
  __threadfence();
  __syncthreads();
  if (tid == 0) ticket_sh = atomicAdd(done, 1);
  __syncthreads();
  if (ticket_sh == (BT_ / 64) - 1) {
    float part = 0.f;
#pragma unroll
    for (int i = 0; i < 4; ++i) {
      const int k = tid + 256 * i;
      const int c = atomicAdd(&counts[k], 0);   // coherent read
      const float p = (float)c * (1.0f / (float)BT_);
      out[HIST_OFF + k] = p;
      if (c > 0) part += p * logf(p);
    }
    cred[tid] = part;
    __syncthreads();
    for (int s = 128; s > 0; s >>= 1) {
      if (tid < s) cred[tid] += cred[tid + s];
      __syncthreads();
    }
    if (tid == 0) {
      out[PERP_OFF] = expf(-cred[0]);
      const float cm = atomicAdd(commit_ws, 0.0f);  // coherent read
      out[LOSS_OFF] = 0.25f * cm / (float)(B_ * D_ * T_);
    }
  }
}

extern "C" void kernel_launch(void* const* d_in, const int* in_sizes, int n_in,
                              void* d_out, int out_size, void* d_ws, size_t ws_size,
                              hipStream_t stream) {
  const float* z_e = (const float*)d_in[0];
  const float* emb = (const float*)d_in[1];
  float* out = (float*)d_out;

  // ws layout (bytes): [0] counts int[1024]; [4096] commit f32; [4100] done int;
  // [8192] e_sq f32[1024]; [12288] ebh ushort[65536]; [143360] ebl ushort[65536]
  int*   counts    = (int*)d_ws;
  float* commit_ws = (float*)((char*)d_ws + 4096);
  int*   done      = (int*)((char*)d_ws + 4100);
  float* e_sq      = (float*)((char*)d_ws + 8192);
  ushort* ebh      = (ushort*)((char*)d_ws + 12288);
  ushort* ebl      = (ushort*)((char*)d_ws + 12288 + 131072);

  prep_kernel<<<16, 256, 0, stream>>>(emb, (int*)d_ws, e_sq, ebh, ebl);
  vq_mfma<<<BT_ / 64, 256, 0, stream>>>(z_e, emb, e_sq, ebh, ebl, out,
                                        commit_ws, counts, done);
}

// Round 7
// 215.235 us; speedup vs baseline: 1.2598x; 1.2598x over previous
//
#include <hip/hip_runtime.h>
#include <hip/hip_bf16.h>
#include <math.h>

#define B_ 16
#define D_ 64
#define T_ 4096
#define K_ 1024
#define BT_ (B_*T_)

// output layout (flat f32, concatenated in return order)
#define ZQ_OFF   0
#define LOSS_OFF 4194304
#define IDX_OFF  4194305
#define PERP_OFF 4259841
#define HIST_OFF 4259842

typedef __attribute__((ext_vector_type(8))) short bf16x8;
typedef __attribute__((ext_vector_type(4))) float f32x4;

__device__ __forceinline__ unsigned umin_(unsigned a, unsigned b){ return a < b ? a : b; }
__device__ __forceinline__ unsigned umax_(unsigned a, unsigned b){ return a > b ? a : b; }

__device__ __forceinline__ ushort f2bf(float x) {
  __hip_bfloat16 h = __float2bfloat16(x);
  return *(ushort*)&h;
}
__device__ __forceinline__ float bf2f(ushort u) {
  __hip_bfloat16 h; *(ushort*)&h = u;
  return __bfloat162float(h);
}

// ---- prep: zero counters + emb f32 -> (ebh, ebl) bf16 split + e_sq ----
// 4096 threads: 1024 codes x 4 chunks of 16 dims
__global__ __launch_bounds__(256) void prep_kernel(
    const float* __restrict__ emb, int* __restrict__ zero_ws,
    float* __restrict__ e_sq, ushort* __restrict__ ebh, ushort* __restrict__ ebl) {
  const int tid = blockIdx.x * 256 + threadIdx.x;
  if (tid < 1026) zero_ws[tid] = 0;   // counts[1024] + commit + done
  const int k = tid >> 2, q = tid & 3;
  const float4* p = (const float4*)(emb + (size_t)k * D_ + q * 16);
  bf16x8 vh[2], vl[2];
  float s = 0.f;
#pragma unroll
  for (int i = 0; i < 4; ++i) {
    float4 v = p[i];
    float xs[4] = {v.x, v.y, v.z, v.w};
#pragma unroll
    for (int j = 0; j < 4; ++j) {
      float x = xs[j];
      ushort hb = f2bf(x);
      ushort lb = f2bf(x - bf2f(hb));
      vh[i >> 1][(i & 1) * 4 + j] = (short)hb;
      vl[i >> 1][(i & 1) * 4 + j] = (short)lb;
      s = fmaf(x, x, s);
    }
  }
  size_t off = (size_t)k * D_ + q * 16;
  *(bf16x8*)(ebh + off) = vh[0];
  *(bf16x8*)(ebh + off + 8) = vh[1];
  *(bf16x8*)(ebl + off) = vl[0];
  *(bf16x8*)(ebl + off + 8) = vl[1];
  s += __shfl_xor(s, 1, 64);
  s += __shfl_xor(s, 2, 64);
  if (q == 0) e_sq[k] = s;
}

__device__ double dist64row(const float* __restrict__ zb, int r,
                            const float* __restrict__ emb, int k) {
  double s = 0.0, dot = 0.0;
#pragma unroll
  for (int d = 0; d < D_; ++d) {
    double e = (double)emb[(size_t)k * D_ + d];
    double x = (double)zb[(size_t)d * T_ + r];
    s += e * e;
    dot += x * e;
  }
  return s - 2.0 * dot;
}

// ---- main: 64 rows/block, 4 waves x 256-code quadrant, MFMA bf16-split ----
// NOTE: no min-waves clause — with one, the allocator capped VGPRs at 84 and
// spilled ~90 regs/thread to scratch (round-6: WRITE_SIZE 18.6->66 MB, 2x slower).
__global__ __launch_bounds__(256) void vq_mfma(
    const float* __restrict__ z_e, const float* __restrict__ emb_f32,
    const float* __restrict__ e_sq, const ushort* __restrict__ ebh,
    const ushort* __restrict__ ebl, float* __restrict__ out,
    float* __restrict__ commit_ws, int* __restrict__ counts,
    int* __restrict__ done) {
  __shared__ ushort Ah[64 * 64];
  __shared__ ushort Al[64 * 64];
  __shared__ unsigned mrg1[4][64];
  __shared__ unsigned mrg2[4][64];
  __shared__ int idx_sh[64];
  __shared__ float cred[256];
  __shared__ int ticket_sh;

  const int tid = threadIdx.x;
  const int lane = tid & 63, wave = tid >> 6;
  const int b = blockIdx.x >> 6;
  const int t0 = (blockIdx.x & 63) << 6;
  const float* zbase = z_e + ((size_t)b * D_) * T_ + t0;

  // Phase 0: stage A tile (64 rows x 64 d) as bf16 hi/lo, XOR-swizzled rows
  {
    const int r = tid & 63, d0 = (tid >> 6) * 16;
    bf16x8 vh[2], vl[2];
#pragma unroll
    for (int j = 0; j < 16; ++j) {
      float x = zbase[(size_t)(d0 + j) * T_ + r];
      ushort hb = f2bf(x);
      vh[j >> 3][j & 7] = (short)hb;
      vl[j >> 3][j & 7] = (short)f2bf(x - bf2f(hb));
    }
    const int base = r * 128 + d0 * 2;
    const int swz = (r & 7) << 4;
    *(bf16x8*)((char*)Ah + (base ^ swz)) = vh[0];
    *(bf16x8*)((char*)Ah + ((base + 16) ^ swz)) = vh[1];
    *(bf16x8*)((char*)Al + (base ^ swz)) = vl[0];
    *(bf16x8*)((char*)Al + ((base + 16) ^ swz)) = vl[1];
  }
  __syncthreads();

  // A fragments to registers (reused for all 16 slabs): [rowfrag][kstep]
  bf16x8 afh[4][2], afl[4][2];
  {
    const int ar = lane & 15;
    const int aks = (lane >> 4) * 8;
#pragma unroll
    for (int f = 0; f < 4; ++f)
#pragma unroll
      for (int ks = 0; ks < 2; ++ks) {
        const int row = f * 16 + ar;
        const int col = ks * 32 + aks;
        const int off = (row * 128 + col * 2) ^ ((row & 7) << 4);
        afh[f][ks] = *(bf16x8*)((char*)Ah + off);
        afl[f][ks] = *(bf16x8*)((char*)Al + off);
      }
  }

  const int cw0 = wave * 256;  // wave's code base (wave-uniform)
  const size_t boff = (size_t)(cw0 + (lane & 15)) * D_ + (lane >> 4) * 8;

  unsigned b1[4][4], b2[4][4];
#pragma unroll
  for (int f = 0; f < 4; ++f)
#pragma unroll
    for (int r = 0; r < 4; ++r) { b1[f][r] = 0xFFFFFFFFu; b2[f][r] = 0xFFFFFFFFu; }

  bf16x8 cbh[2][2], cbl[2][2];
  float cesq[2];
#define LOADB(s, buf)                                                   \
  { size_t o = boff + (size_t)(s) * 16 * D_;                            \
    cbh[buf][0] = *(const bf16x8*)(ebh + o);                            \
    cbh[buf][1] = *(const bf16x8*)(ebh + o + 32);                       \
    cbl[buf][0] = *(const bf16x8*)(ebl + o);                            \
    cbl[buf][1] = *(const bf16x8*)(ebl + o + 32);                       \
    cesq[buf] = e_sq[cw0 + (s) * 16 + (lane & 15)]; }

  LOADB(0, 0);
#pragma unroll
  for (int s = 0; s < 16; ++s) {
    const int cur = s & 1, nxt = cur ^ 1;
    if (s < 15) LOADB(s + 1, nxt);
    f32x4 acc[4];
#pragma unroll
    for (int f = 0; f < 4; ++f) acc[f] = (f32x4){0.f, 0.f, 0.f, 0.f};
#pragma unroll
    for (int f = 0; f < 4; ++f) {
      acc[f] = __builtin_amdgcn_mfma_f32_16x16x32_bf16(afh[f][0], cbh[cur][0], acc[f], 0, 0, 0);
      acc[f] = __builtin_amdgcn_mfma_f32_16x16x32_bf16(afh[f][1], cbh[cur][1], acc[f], 0, 0, 0);
      acc[f] = __builtin_amdgcn_mfma_f32_16x16x32_bf16(afl[f][0], cbh[cur][0], acc[f], 0, 0, 0);
      acc[f] = __builtin_amdgcn_mfma_f32_16x16x32_bf16(afl[f][1], cbh[cur][1], acc[f], 0, 0, 0);
      acc[f] = __builtin_amdgcn_mfma_f32_16x16x32_bf16(afh[f][0], cbl[cur][0], acc[f], 0, 0, 0);
      acc[f] = __builtin_amdgcn_mfma_f32_16x16x32_bf16(afh[f][1], cbl[cur][1], acc[f], 0, 0, 0);
    }
    const unsigned code = (unsigned)(cw0 + s * 16 + (lane & 15));
#pragma unroll
    for (int f = 0; f < 4; ++f) {
#pragma unroll
      for (int r = 0; r < 4; ++r) {
        float dist = fmaf(acc[f][r], -2.0f, cesq[cur]);
        unsigned u = __float_as_uint(dist);
        unsigned sk = u ^ (unsigned)(((int)u >> 31) | 0x80000000);
        unsigned key = (sk & 0xFFFFFC00u) | code;
        unsigned t = umax_(b1[f][r], key);
        b1[f][r] = umin_(b1[f][r], key);
        b2[f][r] = umin_(b2[f][r], t);
      }
    }
  }
#undef LOADB

  // cross-lane top-2 merge across the 16 col-slots (lane bits 0..3)
#pragma unroll
  for (int m = 1; m < 16; m <<= 1) {
#pragma unroll
    for (int f = 0; f < 4; ++f)
#pragma unroll
      for (int r = 0; r < 4; ++r) {
        unsigned o1 = (unsigned)__shfl_xor((int)b1[f][r], m, 64);
        unsigned o2 = (unsigned)__shfl_xor((int)b2[f][r], m, 64);
        unsigned t = umax_(b1[f][r], o1);
        b1[f][r] = umin_(b1[f][r], o1);
        b2[f][r] = umin_(umin_(b2[f][r], o2), t);
      }
  }
  if ((lane & 15) == 0) {
    const int g = lane >> 4;
#pragma unroll
    for (int f = 0; f < 4; ++f)
#pragma unroll
      for (int r = 0; r < 4; ++r) {
        const int row = f * 16 + g * 4 + r;
        mrg1[wave][row] = b1[f][r];
        mrg2[wave][row] = b2[f][r];
      }
  }
  __syncthreads();

  // Phase 2: merge 4 wave-quadrants per row, f64 recheck near-ties, emit index
  if (tid < 64) {
    const int r = tid;
    unsigned B1 = 0xFFFFFFFFu, B2 = 0xFFFFFFFFu;
#pragma unroll
    for (int w = 0; w < 4; ++w) {
      unsigned o1 = mrg1[w][r], o2 = mrg2[w][r];
      unsigned t = umax_(B1, o1);
      B1 = umin_(B1, o1);
      B2 = umin_(umin_(B2, o2), t);
    }
    int i1 = (int)(B1 & 1023u);
    const int i2 = (int)(B2 & 1023u);
    if ((B2 & ~1023u) - (B1 & ~1023u) <= (8u << 10)) {
      double d1 = dist64row(zbase, r, emb_f32, i1);
      double d2 = dist64row(zbase, r, emb_f32, i2);
      if (d2 < d1 || (d2 == d1 && i2 < i1)) i1 = i2;
    }
    idx_sh[r] = i1;
    out[IDX_OFF + b * T_ + t0 + r] = (float)i1;
    atomicAdd(&counts[i1], 1);
  }
  __syncthreads();

  // Phase 3: gather z_q (exact f32), write out, exact commit-loss partial
  {
    const int r = tid & 63, d0 = (tid >> 6) * 16;
    const int k = idx_sh[r];
    const float* ep = emb_f32 + (size_t)k * D_ + d0;
    float c = 0.f;
#pragma unroll
    for (int j = 0; j < 16; ++j) {
      float e = ep[j];
      float x = zbase[(size_t)(d0 + j) * T_ + r];
      out[ZQ_OFF + ((size_t)b * D_ + d0 + j) * T_ + t0 + r] = e;
      float df = x - e;
      c = fmaf(df, df, c);
    }
#pragma unroll
    for (int off = 32; off; off >>= 1) c += __shfl_down(c, off, 64);
    if (lane == 0) cred[wave] = c;
  }
  __syncthreads();
  if (tid == 0) atomicAdd(commit_ws, cred[0] + cred[1] + cred[2] + cred[3]);

  // Folded finalize: last block to finish computes hist/perplexity/loss
  __threadfence();
  __syncthreads();
  if (tid == 0) ticket_sh = atomicAdd(done, 1);
  __syncthreads();
  if (ticket_sh == (BT_ / 64) - 1) {
    float part = 0.f;
#pragma unroll
    for (int i = 0; i < 4; ++i) {
      const int k = tid + 256 * i;
      const int c = atomicAdd(&counts[k], 0);   // coherent read
      const float p = (float)c * (1.0f / (float)BT_);
      out[HIST_OFF + k] = p;
      if (c > 0) part += p * logf(p);
    }
    cred[tid] = part;
    __syncthreads();
    for (int s = 128; s > 0; s >>= 1) {
      if (tid < s) cred[tid] += cred[tid + s];
      __syncthreads();
    }
    if (tid == 0) {
      out[PERP_OFF] = expf(-cred[0]);
      const float cm = atomicAdd(commit_ws, 0.0f);  // coherent read
      out[LOSS_OFF] = 0.25f * cm / (float)(B_ * D_ * T_);
    }
  }
}

extern "C" void kernel_launch(void* const* d_in, const int* in_sizes, int n_in,
                              void* d_out, int out_size, void* d_ws, size_t ws_size,
                              hipStream_t stream) {
  const float* z_e = (const float*)d_in[0];
  const float* emb = (const float*)d_in[1];
  float* out = (float*)d_out;

  // ws layout (bytes): [0] counts int[1024]; [4096] commit f32; [4100] done int;
  // [8192] e_sq f32[1024]; [12288] ebh ushort[65536]; [143360] ebl ushort[65536]
  int*   counts    = (int*)d_ws;
  float* commit_ws = (float*)((char*)d_ws + 4096);
  int*   done      = (int*)((char*)d_ws + 4100);
  float* e_sq      = (float*)((char*)d_ws + 8192);
  ushort* ebh      = (ushort*)((char*)d_ws + 12288);
  ushort* ebl      = (ushort*)((char*)d_ws + 12288 + 131072);

  prep_kernel<<<16, 256, 0, stream>>>(emb, (int*)d_ws, e_sq, ebh, ebl);
  vq_mfma<<<BT_ / 64, 256, 0, stream>>>(z_e, emb, e_sq, ebh, ebl, out,
                                        commit_ws, counts, done);
}

// Round 8
// 169.283 us; speedup vs baseline: 1.6018x; 1.2715x over previous
//
#include <hip/hip_runtime.h>
#include <hip/hip_bf16.h>
#include <math.h>

#define B_ 16
#define D_ 64
#define T_ 4096
#define K_ 1024
#define BT_ (B_*T_)

// output layout (flat f32, concatenated in return order)
#define ZQ_OFF   0
#define LOSS_OFF 4194304
#define IDX_OFF  4194305
#define PERP_OFF 4259841
#define HIST_OFF 4259842

typedef __attribute__((ext_vector_type(8))) short bf16x8;
typedef __attribute__((ext_vector_type(4))) float f32x4;

__device__ __forceinline__ unsigned umin_(unsigned a, unsigned b){ return a < b ? a : b; }
__device__ __forceinline__ unsigned umax_(unsigned a, unsigned b){ return a > b ? a : b; }

__device__ __forceinline__ ushort f2bf(float x) {
  __hip_bfloat16 h = __float2bfloat16(x);
  return *(ushort*)&h;
}
__device__ __forceinline__ float bf2f(ushort u) {
  __hip_bfloat16 h; *(ushort*)&h = u;
  return __bfloat162float(h);
}

// ---- prep: zero counters + emb f32 -> (ebh, ebl) bf16 split + e_sq ----
__global__ __launch_bounds__(256) void prep_kernel(
    const float* __restrict__ emb, int* __restrict__ zero_ws,
    float* __restrict__ e_sq, ushort* __restrict__ ebh, ushort* __restrict__ ebl) {
  const int tid = blockIdx.x * 256 + threadIdx.x;
  if (tid < 1026) zero_ws[tid] = 0;   // counts[1024] + commit (+spare)
  const int k = tid >> 2, q = tid & 3;
  const float4* p = (const float4*)(emb + (size_t)k * D_ + q * 16);
  bf16x8 vh[2], vl[2];
  float s = 0.f;
#pragma unroll
  for (int i = 0; i < 4; ++i) {
    float4 v = p[i];
    float xs[4] = {v.x, v.y, v.z, v.w};
#pragma unroll
    for (int j = 0; j < 4; ++j) {
      float x = xs[j];
      ushort hb = f2bf(x);
      ushort lb = f2bf(x - bf2f(hb));
      vh[i >> 1][(i & 1) * 4 + j] = (short)hb;
      vl[i >> 1][(i & 1) * 4 + j] = (short)lb;
      s = fmaf(x, x, s);
    }
  }
  size_t off = (size_t)k * D_ + q * 16;
  *(bf16x8*)(ebh + off) = vh[0];
  *(bf16x8*)(ebh + off + 8) = vh[1];
  *(bf16x8*)(ebl + off) = vl[0];
  *(bf16x8*)(ebl + off + 8) = vl[1];
  s += __shfl_xor(s, 1, 64);
  s += __shfl_xor(s, 2, 64);
  if (q == 0) e_sq[k] = s;
}

__device__ double dist64row(const float* __restrict__ zb, int r,
                            const float* __restrict__ emb, int k) {
  double s = 0.0, dot = 0.0;
#pragma unroll
  for (int d = 0; d < D_; ++d) {
    double e = (double)emb[(size_t)k * D_ + d];
    double x = (double)zb[(size_t)d * T_ + r];
    s += e * e;
    dot += x * e;
  }
  return s - 2.0 * dot;
}

// ---- main: 32 rows/block, 4 waves x 256-code quadrant, MFMA bf16-split ----
// Round-2 structure (107us measured) + depth-2 B prefetch (triple buffer).
// No min-waves launch bound (round-6: capping VGPR caused spills, 2x slower).
__global__ __launch_bounds__(256) void vq_mfma(
    const float* __restrict__ z_e, const float* __restrict__ emb_f32,
    const float* __restrict__ e_sq, const ushort* __restrict__ ebh,
    const ushort* __restrict__ ebl, float* __restrict__ out,
    float* __restrict__ commit_ws, int* __restrict__ counts) {
  __shared__ ushort Ah[32 * 64];
  __shared__ ushort Al[32 * 64];
  __shared__ unsigned mrg1[4][32];
  __shared__ unsigned mrg2[4][32];
  __shared__ int idx_sh[32];
  __shared__ float cred[256];

  const int tid = threadIdx.x;
  const int lane = tid & 63, wave = tid >> 6;
  const int b = blockIdx.x >> 7;
  const int t0 = (blockIdx.x & 127) << 5;
  const float* zbase = z_e + ((size_t)b * D_) * T_ + t0;

  // Phase 0: stage A tile (32 rows x 64 d) as bf16 hi/lo, XOR-swizzled rows
  {
    const int r = tid & 31, d0 = (tid >> 5) * 8;
    bf16x8 vh, vl;
#pragma unroll
    for (int j = 0; j < 8; ++j) {
      float x = zbase[(size_t)(d0 + j) * T_ + r];
      ushort hb = f2bf(x);
      vh[j] = (short)hb;
      vl[j] = (short)f2bf(x - bf2f(hb));
    }
    const int off = (r * 128 + d0 * 2) ^ ((r & 7) << 4);  // byte offset
    *(bf16x8*)((char*)Ah + off) = vh;
    *(bf16x8*)((char*)Al + off) = vl;
  }
  __syncthreads();

  // A fragments to registers (reused across all 16 slabs): [rowfrag][kstep]
  bf16x8 afh[2][2], afl[2][2];
  {
    const int ar = lane & 15;
    const int aks = (lane >> 4) * 8;
#pragma unroll
    for (int f = 0; f < 2; ++f)
#pragma unroll
      for (int ks = 0; ks < 2; ++ks) {
        const int row = f * 16 + ar;
        const int col = ks * 32 + aks;
        const int off = (row * 128 + col * 2) ^ ((row & 7) << 4);
        afh[f][ks] = *(bf16x8*)((char*)Ah + off);
        afl[f][ks] = *(bf16x8*)((char*)Al + off);
      }
  }

  const int cw0 = wave * 256;  // wave's code base (wave-uniform)
  const size_t boff = (size_t)(cw0 + (lane & 15)) * D_ + (lane >> 4) * 8;

  unsigned b1[2][4], b2[2][4];
#pragma unroll
  for (int f = 0; f < 2; ++f)
#pragma unroll
    for (int r = 0; r < 4; ++r) { b1[f][r] = 0xFFFFFFFFu; b2[f][r] = 0xFFFFFFFFu; }

  // depth-2 prefetch: 3 B-buffer sets, loads issued 2 slabs ahead
  bf16x8 cbh[3][2], cbl[3][2];
  float cesq[3];
#define LOADB(s, buf)                                                   \
  { size_t o = boff + (size_t)(s) * 16 * D_;                            \
    cbh[buf][0] = *(const bf16x8*)(ebh + o);                            \
    cbh[buf][1] = *(const bf16x8*)(ebh + o + 32);                       \
    cbl[buf][0] = *(const bf16x8*)(ebl + o);                            \
    cbl[buf][1] = *(const bf16x8*)(ebl + o + 32);                       \
    cesq[buf] = e_sq[cw0 + (s) * 16 + (lane & 15)]; }

  LOADB(0, 0);
  LOADB(1, 1);
#pragma unroll
  for (int s = 0; s < 16; ++s) {
    const int cur = s % 3;
    if (s < 14) LOADB(s + 2, (s + 2) % 3);
    f32x4 a0 = {0.f, 0.f, 0.f, 0.f}, a1 = {0.f, 0.f, 0.f, 0.f};
    // hi*hi (both ksteps)
    a0 = __builtin_amdgcn_mfma_f32_16x16x32_bf16(afh[0][0], cbh[cur][0], a0, 0, 0, 0);
    a1 = __builtin_amdgcn_mfma_f32_16x16x32_bf16(afh[1][0], cbh[cur][0], a1, 0, 0, 0);
    a0 = __builtin_amdgcn_mfma_f32_16x16x32_bf16(afh[0][1], cbh[cur][1], a0, 0, 0, 0);
    a1 = __builtin_amdgcn_mfma_f32_16x16x32_bf16(afh[1][1], cbh[cur][1], a1, 0, 0, 0);
    // lo*hi
    a0 = __builtin_amdgcn_mfma_f32_16x16x32_bf16(afl[0][0], cbh[cur][0], a0, 0, 0, 0);
    a1 = __builtin_amdgcn_mfma_f32_16x16x32_bf16(afl[1][0], cbh[cur][0], a1, 0, 0, 0);
    a0 = __builtin_amdgcn_mfma_f32_16x16x32_bf16(afl[0][1], cbh[cur][1], a0, 0, 0, 0);
    a1 = __builtin_amdgcn_mfma_f32_16x16x32_bf16(afl[1][1], cbh[cur][1], a1, 0, 0, 0);
    // hi*lo
    a0 = __builtin_amdgcn_mfma_f32_16x16x32_bf16(afh[0][0], cbl[cur][0], a0, 0, 0, 0);
    a1 = __builtin_amdgcn_mfma_f32_16x16x32_bf16(afh[1][0], cbl[cur][0], a1, 0, 0, 0);
    a0 = __builtin_amdgcn_mfma_f32_16x16x32_bf16(afh[0][1], cbl[cur][1], a0, 0, 0, 0);
    a1 = __builtin_amdgcn_mfma_f32_16x16x32_bf16(afh[1][1], cbl[cur][1], a1, 0, 0, 0);

    const unsigned code = (unsigned)(cw0 + s * 16 + (lane & 15));
#pragma unroll
    for (int f = 0; f < 2; ++f) {
#pragma unroll
      for (int r = 0; r < 4; ++r) {
        float av = (f == 0) ? a0[r] : a1[r];
        float dist = fmaf(av, -2.0f, cesq[cur]);
        unsigned u = __float_as_uint(dist);
        unsigned sk = u ^ (unsigned)(((int)u >> 31) | 0x80000000);
        unsigned key = (sk & 0xFFFFFC00u) | code;
        unsigned t = umax_(b1[f][r], key);
        b1[f][r] = umin_(b1[f][r], key);
        b2[f][r] = umin_(b2[f][r], t);
      }
    }
  }
#undef LOADB

  // cross-lane top-2 merge across the 16 col-slots (lanes differing in bits 0..3)
#pragma unroll
  for (int m = 1; m < 16; m <<= 1) {
#pragma unroll
    for (int f = 0; f < 2; ++f)
#pragma unroll
      for (int r = 0; r < 4; ++r) {
        unsigned o1 = (unsigned)__shfl_xor((int)b1[f][r], m, 64);
        unsigned o2 = (unsigned)__shfl_xor((int)b2[f][r], m, 64);
        unsigned t = umax_(b1[f][r], o1);
        b1[f][r] = umin_(b1[f][r], o1);
        b2[f][r] = umin_(umin_(b2[f][r], o2), t);
      }
  }
  if ((lane & 15) == 0) {
    const int g = lane >> 4;
#pragma unroll
    for (int f = 0; f < 2; ++f)
#pragma unroll
      for (int r = 0; r < 4; ++r) {
        const int row = f * 16 + g * 4 + r;
        mrg1[wave][row] = b1[f][r];
        mrg2[wave][row] = b2[f][r];
      }
  }
  __syncthreads();

  // Phase 2: merge 4 wave-quadrants per row, f64 recheck near-ties, emit index
  if (tid < 32) {
    const int r = tid;
    unsigned B1 = 0xFFFFFFFFu, B2 = 0xFFFFFFFFu;
#pragma unroll
    for (int w = 0; w < 4; ++w) {
      unsigned o1 = mrg1[w][r], o2 = mrg2[w][r];
      unsigned t = umax_(B1, o1);
      B1 = umin_(B1, o1);
      B2 = umin_(umin_(B2, o2), t);
    }
    int i1 = (int)(B1 & 1023u);
    const int i2 = (int)(B2 & 1023u);
    // close call (within 8 quantization buckets) -> exact f64 decision
    if ((B2 & ~1023u) - (B1 & ~1023u) <= (8u << 10)) {
      double d1 = dist64row(zbase, r, emb_f32, i1);
      double d2 = dist64row(zbase, r, emb_f32, i2);
      if (d2 < d1 || (d2 == d1 && i2 < i1)) i1 = i2;
    }
    idx_sh[r] = i1;
    out[IDX_OFF + b * T_ + t0 + r] = (float)i1;
    atomicAdd(&counts[i1], 1);
  }
  __syncthreads();

  // Phase 3: gather z_q (exact f32), write out, exact commit-loss partial
  {
    const int r = tid & 31, d0 = (tid >> 5) * 8;
    const int k = idx_sh[r];
    const float* ep = emb_f32 + (size_t)k * D_ + d0;
    float c = 0.f;
#pragma unroll
    for (int j = 0; j < 8; ++j) {
      float e = ep[j];
      float x = zbase[(size_t)(d0 + j) * T_ + r];
      out[ZQ_OFF + ((size_t)b * D_ + d0 + j) * T_ + t0 + r] = e;
      float df = x - e;
      c = fmaf(df, df, c);
    }
    cred[tid] = c;
  }
  __syncthreads();
  for (int s = 128; s > 0; s >>= 1) {
    if (tid < s) cred[tid] += cred[tid + s];
    __syncthreads();
  }
  if (tid == 0) atomicAdd(commit_ws, cred[0]);
}

__global__ __launch_bounds__(1024) void finalize_kernel(
    const int* __restrict__ counts, const float* __restrict__ commit_ws,
    float* __restrict__ out) {
  __shared__ float red[1024];
  const int k = threadIdx.x;
  const int c = counts[k];
  const float p = (float)c / (float)BT_;
  out[HIST_OFF + k] = p;
  red[k] = (c > 0) ? p * logf(p) : 0.0f;
  __syncthreads();
  for (int s = 512; s > 0; s >>= 1) {
    if (k < s) red[k] += red[k + s];
    __syncthreads();
  }
  if (k == 0) {
    out[PERP_OFF] = expf(-red[0]);
    out[LOSS_OFF] = 0.25f * commit_ws[0] / (float)(B_ * D_ * T_);
  }
}

extern "C" void kernel_launch(void* const* d_in, const int* in_sizes, int n_in,
                              void* d_out, int out_size, void* d_ws, size_t ws_size,
                              hipStream_t stream) {
  const float* z_e = (const float*)d_in[0];
  const float* emb = (const float*)d_in[1];
  float* out = (float*)d_out;

  // ws layout (bytes): [0] counts int[1024]; [4096] commit f32;
  // [8192] e_sq f32[1024]; [12288] ebh ushort[65536]; [143360] ebl ushort[65536]
  int*   counts    = (int*)d_ws;
  float* commit_ws = (float*)((char*)d_ws + 4096);
  float* e_sq      = (float*)((char*)d_ws + 8192);
  ushort* ebh      = (ushort*)((char*)d_ws + 12288);
  ushort* ebl      = (ushort*)((char*)d_ws + 12288 + 131072);

  prep_kernel<<<16, 256, 0, stream>>>(emb, (int*)d_ws, e_sq, ebh, ebl);
  vq_mfma<<<BT_ / 32, 256, 0, stream>>>(z_e, emb, e_sq, ebh, ebl, out,
                                        commit_ws, counts);
  finalize_kernel<<<1, 1024, 0, stream>>>(counts, commit_ws, out);
}